// Round 5
// baseline (10292.474 us; speedup 1.0000x reference)
//
#include <hip/hip_runtime.h>

typedef unsigned short u16;
typedef unsigned int u32;
typedef unsigned long long u64;
typedef unsigned char u8;
typedef __bf16 bf16x8 __attribute__((ext_vector_type(8)));
typedef float f32x4 __attribute__((ext_vector_type(4)));
typedef u32 u32x4 __attribute__((ext_vector_type(4)));

#define T_LEN 512
#define BATCH 64
#define FIN 128
#define UNITS 1024
#define H_STRIDE 65536              // elements per parity buffer (64 rows * 1024)

// ---- workspace layout (bytes) ----
#define O_BAR   0
#define SZ_BAR  4096
#define O_XBF   SZ_BAR
#define SZ_XBF  (T_LEN*BATCH*FIN*2)
#define O_WP0   (O_XBF + SZ_XBF)
#define SZ_WP0  (1152*4096*2)
#define O_WP1   (O_WP0 + SZ_WP0)
#define SZ_WP1  (2048*4096*2)
#define O_WGFC  (O_WP1 + SZ_WP1)
#define SZ_WGFC (16384*2)
#define O_S1    (O_WGFC + SZ_WGFC)
#define SZ_S1   (4096*4)
#define O_B1C   (O_S1 + SZ_S1)
#define SZ_B1C  (4096*4)
#define O_SFC   (O_B1C + SZ_B1C)
#define SZ_SFC  64
#define O_BFCF  (O_SFC + SZ_SFC)
#define SZ_BFCF 64
#define O_H0    (O_BFCF + SZ_BFCF)
#define SZ_H    (2*H_STRIDE*2)      // 2 parities
#define O_H1    (O_H0 + SZ_H)
#define WS_NEED (O_H1 + SZ_H)

__device__ __forceinline__ float bf2f(u16 s) {
  u32 u = ((u32)s) << 16;
  return __builtin_bit_cast(float, u);
}
__device__ __forceinline__ u16 f2bf(float f) {
  u32 u = __builtin_bit_cast(u32, f);
  u32 r = (u + 0x7FFFu + ((u >> 16) & 1u)) >> 16;
  return (u16)r;
}
__device__ __forceinline__ float sigm(float x) { return 1.0f / (1.0f + __expf(-x)); }
__device__ __forceinline__ float tanhft(float x) { return 1.0f - 2.0f / (__expf(2.0f * x) + 1.0f); }

__device__ __forceinline__ void sth(u16* q, u16 v) {
  __hip_atomic_store(q, v, __ATOMIC_RELAXED, __HIP_MEMORY_SCOPE_AGENT);
}

// 8x dwordx4 L2-bypassing loads, one vmcnt(0): single LLC round-trip gather.
__device__ __forceinline__ void ldh2x64(const u16* qa, const u16* qb,
    u32x4& a0, u32x4& a1, u32x4& a2, u32x4& a3,
    u32x4& b0, u32x4& b1, u32x4& b2, u32x4& b3) {
  asm volatile(
    "global_load_dwordx4 %0, %8, off sc0 sc1\n\t"
    "global_load_dwordx4 %1, %8, off offset:512 sc0 sc1\n\t"
    "global_load_dwordx4 %2, %8, off offset:1024 sc0 sc1\n\t"
    "global_load_dwordx4 %3, %8, off offset:1536 sc0 sc1\n\t"
    "global_load_dwordx4 %4, %9, off sc0 sc1\n\t"
    "global_load_dwordx4 %5, %9, off offset:512 sc0 sc1\n\t"
    "global_load_dwordx4 %6, %9, off offset:1024 sc0 sc1\n\t"
    "global_load_dwordx4 %7, %9, off offset:1536 sc0 sc1\n\t"
    "s_waitcnt vmcnt(0)"
    : "=&v"(a0), "=&v"(a1), "=&v"(a2), "=&v"(a3),
      "=&v"(b0), "=&v"(b1), "=&v"(b2), "=&v"(b3)
    : "v"(qa), "v"(qb) : "memory");
}
__device__ __forceinline__ void ldh1x64(const u16* q,
    u32x4& a0, u32x4& a1, u32x4& a2, u32x4& a3) {
  asm volatile(
    "global_load_dwordx4 %0, %4, off sc0 sc1\n\t"
    "global_load_dwordx4 %1, %4, off offset:512 sc0 sc1\n\t"
    "global_load_dwordx4 %2, %4, off offset:1024 sc0 sc1\n\t"
    "global_load_dwordx4 %3, %4, off offset:1536 sc0 sc1\n\t"
    "s_waitcnt vmcnt(0)"
    : "=&v"(a0), "=&v"(a1), "=&v"(a2), "=&v"(a3)
    : "v"(q) : "memory");
}

// ---------------- prep kernels ----------------
__global__ void k_zero(u32* p, int n) {
  int i = blockIdx.x * 256 + threadIdx.x;
  if (i < n) p[i] = 0u;
}

__global__ void k_pack_x(const float* __restrict__ src, u16* __restrict__ dst) {
  int i = blockIdx.x * 256 + threadIdx.x;      // < 512*64*128
  int f = i & 127, tb = i >> 7;
  int b = tb & 63, t = tb >> 6;
  dst[i] = f2bf(src[(b * T_LEN + t) * FIN + f]);
}

// Wp0: [ug][nt][ktg(36)][lane][8] over K=[W0(128);U0(1024)], cols unit-gate interleaved
__global__ void k_pack_w0(const float* __restrict__ W0, const float* __restrict__ U0,
                          u16* __restrict__ dst) {
  int i = blockIdx.x * 256 + threadIdx.x;      // < 4096*1152
  int j = i & 7, lane = (i >> 3) & 63, rest = i >> 9;
  int ktg = rest % 36, tmp = rest / 36;
  int nt = tmp & 3, ug = tmp >> 2;
  int k = ktg * 32 + ((lane >> 4) << 3) + j;
  int rr = nt * 16 + (lane & 15);
  int gate = rr & 3, ul = rr >> 2;
  int col = gate * 1024 + ug * 16 + ul;
  float v = (k < FIN) ? W0[k * 4096 + col] : U0[(k - FIN) * 4096 + col];
  dst[i] = f2bf(v);
}

// Wp1: [ug][nt][ktg(64)][lane][8] over K=[g0*W1(1024);U1(1024)]  (LN0 folded into W1)
__global__ void k_pack_w1(const float* __restrict__ W1, const float* __restrict__ U1,
                          const float* __restrict__ g0, u16* __restrict__ dst) {
  int i = blockIdx.x * 256 + threadIdx.x;      // < 4096*2048
  int j = i & 7, lane = (i >> 3) & 63, rest = i >> 9;
  int ktg = rest & 63, tmp = rest >> 6;
  int nt = tmp & 3, ug = tmp >> 2;
  int k = ktg * 32 + ((lane >> 4) << 3) + j;
  int rr = nt * 16 + (lane & 15);
  int gate = rr & 3, ul = rr >> 2;
  int col = gate * 1024 + ug * 16 + ul;
  float v = (k < UNITS) ? g0[k] * W1[k * 4096 + col] : U1[(k - UNITS) * 4096 + col];
  dst[i] = f2bf(v);
}

// S1[n] = sum_k g0[k]*W1[k][n];  B1C[n] = b1[n] + sum_k be0[k]*W1[k][n]
__global__ void k_pack_s1(const float* __restrict__ W1, const float* __restrict__ g0,
                          const float* __restrict__ be0, const float* __restrict__ b1,
                          float* __restrict__ S1, float* __restrict__ B1C) {
  int n = blockIdx.x * 256 + threadIdx.x;      // < 4096
  float s = 0.f, c = 0.f;
  for (int k = 0; k < 1024; ++k) {
    float w = W1[k * 4096 + n];
    s += g0[k] * w;
    c += be0[k] * w;
  }
  S1[n] = s;
  B1C[n] = b1[n] + c;
}

// wgfc: B-frags (16x16x32) of g1*Wfc: [s(32)][lane][8], c=lane&15, k=s*32+(lane>>4)*8+j
__global__ void k_pack_wgfc(const float* __restrict__ Wfc, const float* __restrict__ g1,
                            u16* __restrict__ dst) {
  int i = blockIdx.x * 256 + threadIdx.x;      // < 16384
  int j = i & 7, lane = (i >> 3) & 63, s = i >> 9;
  int c = lane & 15;
  int k = s * 32 + ((lane >> 4) << 3) + j;
  dst[i] = f2bf(g1[k] * Wfc[k * 16 + c]);
}

__global__ void k_pack_sfc(const float* __restrict__ Wfc, const float* __restrict__ g1,
                           const float* __restrict__ be1, const float* __restrict__ bfc,
                           float* __restrict__ Sfc, float* __restrict__ Bf) {
  int c = threadIdx.x;
  if (c < 16) {
    float s = 0.f, b = 0.f;
    for (int k = 0; k < 1024; ++k) {
      float w = Wfc[k * 16 + c];
      s += g1[k] * w;
      b += be1[k] * w;
    }
    Sfc[c] = s;
    Bf[c] = bfc[c] + b;
  }
}

// ---------------- persistent kernel ----------------
struct KP {
  const u16* xbf; const u16* wp0; const u16* wp1; const u16* wgfc;
  u16* h0; u16* h1; u8* bar;
  const float* b0; const float* s1; const float* b1c;
  const float* sfc; const float* bfcf;
  float* out;
};

__device__ __forceinline__ void accst4(u32x4 v, float& s1, float& s2) {
#pragma unroll
  for (int e = 0; e < 4; ++e) {
    float f0 = bf2f((u16)(v[e] & 0xffffu));
    float f1 = bf2f((u16)(v[e] >> 16));
    s1 += f0 + f1;
    s2 += f0 * f0 + f1 * f1;
  }
}

// byte-flag barrier: 64 flags of one bg packed in one 64B line. Single hop:
// store own byte (RELEASE), poll whole line with one coalesced 64-lane ubyte
// load. Epochs mod 256; skew is +-1 so wrapped signed compare is safe.
// Caller brackets with __syncthreads (entry sync drains vmcnt => h stores
// visible at LLC before the flag store).
__device__ __forceinline__ void flag_set(u8* fl, int ug, u32 ep) {
  __hip_atomic_store(fl + ug, (u8)ep, __ATOMIC_RELEASE, __HIP_MEMORY_SCOPE_AGENT);
}
__device__ __forceinline__ void flag_wait(u8* fl, int lane, u32 ep) {
  u8 tgt = (u8)ep;
  for (;;) {
    u8 v = __hip_atomic_load(fl + lane, __ATOMIC_RELAXED, __HIP_MEMORY_SCOPE_AGENT);
    if (__ballot((signed char)(v - tgt) >= 0) == ~0ull) break;
    __builtin_amdgcn_s_sleep(4);
  }
}

// FC + softmax for 16 rows, wave0 only, via MFMA on raw h1 (LN folded into
// wgB/sfc/bfcf). Runs inside the barrier wait window — off the critical path.
__device__ __forceinline__ void fc_wave0(int lane, int bg, int tout,
    const u16 (*bufB)[1032], const u16* wgB, const float* mu_s, const float* sg_s,
    float sfc_l, float bfc_l, float* __restrict__ out) {
  const int am = lane & 15, aq = (lane >> 4) << 3;
  f32x4 acc = {0.f, 0.f, 0.f, 0.f};
#pragma unroll
  for (int s = 0; s < 32; ++s) {
    bf16x8 a = *(const bf16x8*)&bufB[am][s * 32 + aq];
    bf16x8 b = *(const bf16x8*)&wgB[s * 512 + lane * 8];
    acc = __builtin_amdgcn_mfma_f32_16x16x32_bf16(a, b, acc, 0, 0, 0);
  }
  const int q = lane >> 4;
#pragma unroll
  for (int i = 0; i < 4; ++i) {
    int r = q * 4 + i;
    float rs = sg_s[r], mu = mu_s[r];
    float lg = rs * acc[i] - rs * mu * sfc_l + bfc_l;   // logits[r][c=am]
    float mx = lg;
#pragma unroll
    for (int m = 1; m <= 8; m <<= 1) mx = fmaxf(mx, __shfl_xor(mx, m));
    float e = __expf(lg - mx), ss = e;
#pragma unroll
    for (int m = 1; m <= 8; m <<= 1) ss += __shfl_xor(ss, m);
    out[((size_t)(bg * 16 + r) * T_LEN + tout) * 16 + am] = e / ss;
  }
}

__global__ void __launch_bounds__(512, 2) k_persist(KP p) {
  const int tid = threadIdx.x;
  const int ug = blockIdx.x & 63, bg = blockIdx.x >> 6;
  const int lane = tid & 63, wv = tid >> 6;
  const int nt = wv & 3, kh = wv >> 2;

  __shared__ __align__(16) u16 bufA[16][1032];  // raw h0(t-1), carried across steps
  __shared__ __align__(16) u16 bufB[16][1032];  // raw h1(t-1)
  __shared__ __align__(16) u16 wgB[16384];      // g1*Wfc B-frags, resident
  __shared__ float zb[2][16][68];               // kh-partial z tiles
  __shared__ float b0s[64], b1s[64], S1b[64];
  __shared__ float al_s[16], be_s[16];          // LN0(h0(t)) fold: alpha=rs, beta=-rs*mu
  __shared__ float mu_s[16], sg_s[16];          // LN1 stats of h1(t-1) (for FC)

  if (tid < 64) {
    int gate = tid & 3, ul = tid >> 2;
    int col = gate * 1024 + ug * 16 + ul;
    b0s[tid] = p.b0[col];
    b1s[tid] = p.b1c[col];
    S1b[tid] = p.s1[col];
  }
  for (int i = tid * 8; i < 16384; i += 4096)
    *(uint4*)&wgB[i] = *(const uint4*)(p.wgfc + i);
  {
    u32* za = (u32*)&bufA[0][0];
    u32* zc = (u32*)&bufB[0][0];
    for (int i = tid; i < 16 * 1032 / 2; i += 512) { za[i] = 0u; zc[i] = 0u; }
  }
  const float sfc_l = p.sfc[lane & 15], bfc_l = p.bfcf[lane & 15];

  // resident weight fragments (bf16, MFMA B-operand order); live in the unified
  // VGPR/AGPR file under launch_bounds(512,2) (R1 lesson: default cap => spill)
  bf16x8 w0r[18], w1r[32];
  {
    const u16* q0 = p.wp0 + (size_t)(((ug * 4 + nt) * 36 + kh * 18) * 64 + lane) * 8;
#pragma unroll
    for (int s = 0; s < 18; ++s)
      w0r[s] = __builtin_bit_cast(bf16x8, *(const uint4*)(q0 + (size_t)s * 512));
    const u16* q1 = p.wp1 + (size_t)(((ug * 4 + nt) * 64 + kh * 32) * 64 + lane) * 8;
#pragma unroll
    for (int s = 0; s < 32; ++s)
      w1r[s] = __builtin_bit_cast(bf16x8, *(const uint4*)(q1 + (size_t)s * 512));
  }

  u8* fl = p.bar + bg * 128;                    // 64 flag bytes per bg, own line

  float c0 = 0.f, c1 = 0.f;                     // cell state, tid<256: (row=tid>>4, unit=tid&15)
  const int gr = tid >> 4, gu = tid & 15;
  const int srow = tid >> 5, ssub = tid & 31;   // row-staging map (32 thr/row)
  const int am = lane & 15, aq = (lane >> 4) << 3;  // A-frag: row=lane&15, k += (lane>>4)*8

  __syncthreads();

  for (int t = 0; t < T_LEN; ++t) {
    const int cur = t & 1, rd = cur ^ 1;

    // ======== L0 MFMA: z0 = [x(t) | h0(t-1)] @ Wp0 ========
    f32x4 acc0 = {0.f, 0.f, 0.f, 0.f};
    if (kh == 0) {
      const u16* xr = p.xbf + (size_t)(t * 64 + bg * 16 + am) * FIN + aq;
#pragma unroll
      for (int s = 0; s < 4; ++s) {            // k in [0,128): x
        bf16x8 a = __builtin_bit_cast(bf16x8, *(const uint4*)(xr + s * 32));
        acc0 = __builtin_amdgcn_mfma_f32_16x16x32_bf16(a, w0r[s], acc0, 0, 0, 0);
      }
#pragma unroll
      for (int s = 4; s < 18; ++s) {           // k in [128,576): h0[0..448)
        bf16x8 a = __builtin_bit_cast(bf16x8, *(const uint4*)&bufA[am][s * 32 + aq - 128]);
        acc0 = __builtin_amdgcn_mfma_f32_16x16x32_bf16(a, w0r[s], acc0, 0, 0, 0);
      }
    } else {
#pragma unroll
      for (int s = 0; s < 18; ++s) {           // k in [576,1152): h0[448..1024)
        bf16x8 a = __builtin_bit_cast(bf16x8, *(const uint4*)&bufA[am][448 + s * 32 + aq]);
        acc0 = __builtin_amdgcn_mfma_f32_16x16x32_bf16(a, w0r[s], acc0, 0, 0, 0);
      }
    }
#pragma unroll
    for (int i = 0; i < 4; ++i)
      zb[kh][(lane >> 4) * 4 + i][nt * 16 + (lane & 15)] = acc0[i];
    __syncthreads();

    // ======== gates layer0 -> coherent store of h0(t) (parity cur) ========
    if (tid < 256) {
      const float* zr0 = &zb[0][gr][gu * 4];
      const float* zr1 = &zb[1][gr][gu * 4];
      float zi = zr0[0] + zr1[0] + b0s[gu * 4 + 0];
      float zf = zr0[1] + zr1[1] + b0s[gu * 4 + 1];
      float zg = zr0[2] + zr1[2] + b0s[gu * 4 + 2];
      float zo = zr0[3] + zr1[3] + b0s[gu * 4 + 3];
      float gi = sigm(zi), gf = sigm(zf), gg = tanhft(zg), go = sigm(zo);
      c0 = gf * c0 + gi * gg;
      float h = go * tanhft(c0);
      sth(p.h0 + (size_t)cur * H_STRIDE + (size_t)(bg * 16 + gr) * UNITS + ug * 16 + gu,
          f2bf(h));
    }
    __syncthreads();                            // drains h0 stores (vmcnt(0) before s_barrier)

    // ---- barrier; FC(t-2) hides in the wait window on wave0 ----
    if (wv == 0) {
      flag_set(fl, ug, (u32)(t + 1));
      if (ug < 16 && t >= 2)
        fc_wave0(lane, bg, t - 2, bufB, wgB, mu_s, sg_s, sfc_l, bfc_l, p.out);
      flag_wait(fl, lane, (u32)(t + 1));
    }
    __syncthreads();

    // ======== overlapped gather: h0(t)[cur] + h1(t-1)[rd], one LLC round-trip ========
    {
      const u16* h0r = p.h0 + (size_t)cur * H_STRIDE + (size_t)(bg * 16 + srow) * UNITS + ssub * 8;
      const u16* h1r = p.h1 + (size_t)rd  * H_STRIDE + (size_t)(bg * 16 + srow) * UNITS + ssub * 8;
      u32x4 a0, a1, a2, a3, b0, b1, b2, b3;
      ldh2x64(h0r, h1r, a0, a1, a2, a3, b0, b1, b2, b3);

      float s1 = 0.f, s2 = 0.f;
      accst4(a0, s1, s2); accst4(a1, s1, s2); accst4(a2, s1, s2); accst4(a3, s1, s2);
#pragma unroll
      for (int m = 1; m <= 16; m <<= 1) { s1 += __shfl_xor(s1, m); s2 += __shfl_xor(s2, m); }
      if (ssub == 0) {
        float mu = s1 * (1.0f / 1024.0f);
        float rs = rsqrtf(s2 * (1.0f / 1024.0f) - mu * mu + 1e-3f);
        al_s[srow] = rs;
        be_s[srow] = -rs * mu;
      }
      float u1 = 0.f, u2 = 0.f;
      accst4(b0, u1, u2); accst4(b1, u1, u2); accst4(b2, u1, u2); accst4(b3, u1, u2);
#pragma unroll
      for (int m = 1; m <= 16; m <<= 1) { u1 += __shfl_xor(u1, m); u2 += __shfl_xor(u2, m); }
      if (ssub == 0) {
        float mu = u1 * (1.0f / 1024.0f);
        mu_s[srow] = mu;
        sg_s[srow] = rsqrtf(u2 * (1.0f / 1024.0f) - mu * mu + 1e-3f);
      }
      *(u32x4*)&bufA[srow][ssub * 8]       = a0;
      *(u32x4*)&bufA[srow][256 + ssub * 8] = a1;
      *(u32x4*)&bufA[srow][512 + ssub * 8] = a2;
      *(u32x4*)&bufA[srow][768 + ssub * 8] = a3;
      *(u32x4*)&bufB[srow][ssub * 8]       = b0;
      *(u32x4*)&bufB[srow][256 + ssub * 8] = b1;
      *(u32x4*)&bufB[srow][512 + ssub * 8] = b2;
      *(u32x4*)&bufB[srow][768 + ssub * 8] = b3;
    }
    __syncthreads();

    // ======== L1 MFMA on RAW h: kh0 = h0(t)@(g0*W1), kh1 = h1(t-1)@U1 ========
    f32x4 acc1 = {0.f, 0.f, 0.f, 0.f};
    if (kh == 0) {
#pragma unroll
      for (int s = 0; s < 32; ++s) {
        bf16x8 a = __builtin_bit_cast(bf16x8, *(const uint4*)&bufA[am][s * 32 + aq]);
        acc1 = __builtin_amdgcn_mfma_f32_16x16x32_bf16(a, w1r[s], acc1, 0, 0, 0);
      }
    } else {
#pragma unroll
      for (int s = 0; s < 32; ++s) {
        bf16x8 a = __builtin_bit_cast(bf16x8, *(const uint4*)&bufB[am][s * 32 + aq]);
        acc1 = __builtin_amdgcn_mfma_f32_16x16x32_bf16(a, w1r[s], acc1, 0, 0, 0);
      }
    }
#pragma unroll
    for (int i = 0; i < 4; ++i)
      zb[kh][(lane >> 4) * 4 + i][nt * 16 + (lane & 15)] = acc1[i];
    __syncthreads();

    // ======== gates layer1 (LN0 applied as per-row affine) -> h1(t) store ========
    if (tid < 256) {
      const float al = al_s[gr], be = be_s[gr];
      const float* zr0 = &zb[0][gr][gu * 4];
      const float* zr1 = &zb[1][gr][gu * 4];
      float zi = al * zr0[0] + be * S1b[gu * 4 + 0] + zr1[0] + b1s[gu * 4 + 0];
      float zf = al * zr0[1] + be * S1b[gu * 4 + 1] + zr1[1] + b1s[gu * 4 + 1];
      float zg = al * zr0[2] + be * S1b[gu * 4 + 2] + zr1[2] + b1s[gu * 4 + 2];
      float zo = al * zr0[3] + be * S1b[gu * 4 + 3] + zr1[3] + b1s[gu * 4 + 3];
      float gi = sigm(zi), gf = sigm(zf), gg = tanhft(zg), go = sigm(zo);
      c1 = gf * c1 + gi * gg;
      float h = go * tanhft(c1);
      sth(p.h1 + (size_t)cur * H_STRIDE + (size_t)(bg * 16 + gr) * UNITS + ug * 16 + gu,
          f2bf(h));
    }
    __syncthreads();  // R4 race fix: protect zb from next step's L0 writes
  }

  // ======== epilogue: FC(510) from current bufB; then gather h1(511) -> FC(511) ====
  if (wv == 0) {
    flag_set(fl, ug, (u32)(T_LEN + 1));
    if (ug < 16)
      fc_wave0(lane, bg, T_LEN - 2, bufB, wgB, mu_s, sg_s, sfc_l, bfc_l, p.out);
    flag_wait(fl, lane, (u32)(T_LEN + 1));
  }
  __syncthreads();
  {
    const u16* h1r = p.h1 + (size_t)((T_LEN - 1) & 1) * H_STRIDE
                   + (size_t)(bg * 16 + srow) * UNITS + ssub * 8;
    u32x4 b0, b1, b2, b3;
    ldh1x64(h1r, b0, b1, b2, b3);
    float u1 = 0.f, u2 = 0.f;
    accst4(b0, u1, u2); accst4(b1, u1, u2); accst4(b2, u1, u2); accst4(b3, u1, u2);
#pragma unroll
    for (int m = 1; m <= 16; m <<= 1) { u1 += __shfl_xor(u1, m); u2 += __shfl_xor(u2, m); }
    if (ssub == 0) {
      float mu = u1 * (1.0f / 1024.0f);
      mu_s[srow] = mu;
      sg_s[srow] = rsqrtf(u2 * (1.0f / 1024.0f) - mu * mu + 1e-3f);
    }
    *(u32x4*)&bufB[srow][ssub * 8]       = b0;
    *(u32x4*)&bufB[srow][256 + ssub * 8] = b1;
    *(u32x4*)&bufB[srow][512 + ssub * 8] = b2;
    *(u32x4*)&bufB[srow][768 + ssub * 8] = b3;
  }
  __syncthreads();
  if (ug < 16 && wv == 0)
    fc_wave0(lane, bg, T_LEN - 1, bufB, wgB, mu_s, sg_s, sfc_l, bfc_l, p.out);
}

extern "C" void kernel_launch(void* const* d_in, const int* in_sizes, int n_in,
                              void* d_out, int out_size, void* d_ws, size_t ws_size,
                              hipStream_t stream) {
  (void)in_sizes; (void)n_in; (void)out_size;
  if (ws_size < (size_t)WS_NEED) return;

  const float* inp = (const float*)d_in[0];
  const float* W0  = (const float*)d_in[1];
  const float* U0  = (const float*)d_in[2];
  const float* b0  = (const float*)d_in[3];
  const float* g0  = (const float*)d_in[4];
  const float* be0 = (const float*)d_in[5];
  const float* W1  = (const float*)d_in[6];
  const float* U1  = (const float*)d_in[7];
  const float* b1  = (const float*)d_in[8];
  const float* g1  = (const float*)d_in[9];
  const float* be1 = (const float*)d_in[10];
  const float* Wfc = (const float*)d_in[11];
  const float* bfc = (const float*)d_in[12];

  char* ws = (char*)d_ws;
  u8*  bar  = (u8*)(ws + O_BAR);
  u16* xbf  = (u16*)(ws + O_XBF);
  u16* wp0  = (u16*)(ws + O_WP0);
  u16* wp1  = (u16*)(ws + O_WP1);
  u16* wgfc = (u16*)(ws + O_WGFC);
  float* S1   = (float*)(ws + O_S1);
  float* B1C  = (float*)(ws + O_B1C);
  float* Sfc  = (float*)(ws + O_SFC);
  float* Bf   = (float*)(ws + O_BFCF);
  u16* h0   = (u16*)(ws + O_H0);
  u16* h1   = (u16*)(ws + O_H1);

  k_zero<<<4, 256, 0, stream>>>((u32*)bar, 1024);
  k_zero<<<512, 256, 0, stream>>>((u32*)(ws + O_H0), (SZ_H + SZ_H) / 4);
  k_pack_x<<<16384, 256, 0, stream>>>(inp, xbf);
  k_pack_w0<<<18432, 256, 0, stream>>>(W0, U0, wp0);
  k_pack_w1<<<32768, 256, 0, stream>>>(W1, U1, g0, wp1);
  k_pack_s1<<<16, 256, 0, stream>>>(W1, g0, be0, b1, S1, B1C);
  k_pack_wgfc<<<64, 256, 0, stream>>>(Wfc, g1, wgfc);
  k_pack_sfc<<<1, 64, 0, stream>>>(Wfc, g1, be1, bfc, Sfc, Bf);

  KP p;
  p.xbf = xbf; p.wp0 = wp0; p.wp1 = wp1; p.wgfc = wgfc;
  p.h0 = h0; p.h1 = h1; p.bar = bar;
  p.b0 = b0; p.s1 = S1; p.b1c = B1C;
  p.sfc = Sfc; p.bfcf = Bf;
  p.out = (float*)d_out;

  void* args[] = { &p };
  hipLaunchCooperativeKernel((const void*)k_persist, dim3(256), dim3(512), args, 0, stream);
}

// Round 6
// 7040.631 us; speedup vs baseline: 1.4619x; 1.4619x over previous
//
#include <hip/hip_runtime.h>

typedef unsigned short u16;
typedef unsigned int u32;
typedef unsigned long long u64;
typedef __bf16 bf16x8 __attribute__((ext_vector_type(8)));
typedef float f32x4 __attribute__((ext_vector_type(4)));
typedef u32 u32x4 __attribute__((ext_vector_type(4)));

#define T_LEN 512
#define BATCH 64
#define FIN 128
#define UNITS 1024
#define H_STRIDE 65536              // elements per parity buffer (64 rows * 1024)

// ---- workspace layout (bytes) ----
#define O_BAR   0
#define SZ_BAR  65536               // 4 bg * (64 flags * 128B) + gen lines
#define O_XBF   SZ_BAR
#define SZ_XBF  (T_LEN*BATCH*FIN*2)
#define O_WP0   (O_XBF + SZ_XBF)
#define SZ_WP0  (1152*4096*2)
#define O_WP1   (O_WP0 + SZ_WP0)
#define SZ_WP1  (2048*4096*2)
#define O_WGFC  (O_WP1 + SZ_WP1)
#define SZ_WGFC (16384*2)
#define O_S1    (O_WGFC + SZ_WGFC)
#define SZ_S1   (4096*4)
#define O_B1C   (O_S1 + SZ_S1)
#define SZ_B1C  (4096*4)
#define O_SFC   (O_B1C + SZ_B1C)
#define SZ_SFC  64
#define O_BFCF  (O_SFC + SZ_SFC)
#define SZ_BFCF 64
#define O_H0    (O_BFCF + SZ_BFCF)
#define SZ_H    (2*H_STRIDE*2)      // 2 parities
#define O_H1    (O_H0 + SZ_H)
#define WS_NEED (O_H1 + SZ_H)

__device__ __forceinline__ float bf2f(u16 s) {
  u32 u = ((u32)s) << 16;
  return __builtin_bit_cast(float, u);
}
__device__ __forceinline__ u16 f2bf(float f) {
  u32 u = __builtin_bit_cast(u32, f);
  u32 r = (u + 0x7FFFu + ((u >> 16) & 1u)) >> 16;
  return (u16)r;
}
__device__ __forceinline__ float sigm(float x) { return 1.0f / (1.0f + __expf(-x)); }
__device__ __forceinline__ float tanhft(float x) { return 1.0f - 2.0f / (__expf(2.0f * x) + 1.0f); }

__device__ __forceinline__ void sth(u16* q, u16 v) {
  __hip_atomic_store(q, v, __ATOMIC_RELAXED, __HIP_MEMORY_SCOPE_AGENT);
}

// 8x dwordx4 L2-bypassing loads, one vmcnt(0): single LLC round-trip gather.
__device__ __forceinline__ void ldh2x64(const u16* qa, const u16* qb,
    u32x4& a0, u32x4& a1, u32x4& a2, u32x4& a3,
    u32x4& b0, u32x4& b1, u32x4& b2, u32x4& b3) {
  asm volatile(
    "global_load_dwordx4 %0, %8, off sc0 sc1\n\t"
    "global_load_dwordx4 %1, %8, off offset:512 sc0 sc1\n\t"
    "global_load_dwordx4 %2, %8, off offset:1024 sc0 sc1\n\t"
    "global_load_dwordx4 %3, %8, off offset:1536 sc0 sc1\n\t"
    "global_load_dwordx4 %4, %9, off sc0 sc1\n\t"
    "global_load_dwordx4 %5, %9, off offset:512 sc0 sc1\n\t"
    "global_load_dwordx4 %6, %9, off offset:1024 sc0 sc1\n\t"
    "global_load_dwordx4 %7, %9, off offset:1536 sc0 sc1\n\t"
    "s_waitcnt vmcnt(0)"
    : "=&v"(a0), "=&v"(a1), "=&v"(a2), "=&v"(a3),
      "=&v"(b0), "=&v"(b1), "=&v"(b2), "=&v"(b3)
    : "v"(qa), "v"(qb) : "memory");
}
__device__ __forceinline__ void ldh1x64(const u16* q,
    u32x4& a0, u32x4& a1, u32x4& a2, u32x4& a3) {
  asm volatile(
    "global_load_dwordx4 %0, %4, off sc0 sc1\n\t"
    "global_load_dwordx4 %1, %4, off offset:512 sc0 sc1\n\t"
    "global_load_dwordx4 %2, %4, off offset:1024 sc0 sc1\n\t"
    "global_load_dwordx4 %3, %4, off offset:1536 sc0 sc1\n\t"
    "s_waitcnt vmcnt(0)"
    : "=&v"(a0), "=&v"(a1), "=&v"(a2), "=&v"(a3)
    : "v"(q) : "memory");
}

// ---------------- prep kernels ----------------
__global__ void k_zero(u32* p, int n) {
  int i = blockIdx.x * 256 + threadIdx.x;
  if (i < n) p[i] = 0u;
}

__global__ void k_pack_x(const float* __restrict__ src, u16* __restrict__ dst) {
  int i = blockIdx.x * 256 + threadIdx.x;      // < 512*64*128
  int f = i & 127, tb = i >> 7;
  int b = tb & 63, t = tb >> 6;
  dst[i] = f2bf(src[(b * T_LEN + t) * FIN + f]);
}

// Wp0: [ug][nt][ktg(36)][lane][8] over K=[W0(128);U0(1024)], cols unit-gate interleaved
__global__ void k_pack_w0(const float* __restrict__ W0, const float* __restrict__ U0,
                          u16* __restrict__ dst) {
  int i = blockIdx.x * 256 + threadIdx.x;      // < 4096*1152
  int j = i & 7, lane = (i >> 3) & 63, rest = i >> 9;
  int ktg = rest % 36, tmp = rest / 36;
  int nt = tmp & 3, ug = tmp >> 2;
  int k = ktg * 32 + ((lane >> 4) << 3) + j;
  int rr = nt * 16 + (lane & 15);
  int gate = rr & 3, ul = rr >> 2;
  int col = gate * 1024 + ug * 16 + ul;
  float v = (k < FIN) ? W0[k * 4096 + col] : U0[(k - FIN) * 4096 + col];
  dst[i] = f2bf(v);
}

// Wp1: [ug][nt][ktg(64)][lane][8] over K=[g0*W1(1024);U1(1024)]  (LN0 folded into W1)
__global__ void k_pack_w1(const float* __restrict__ W1, const float* __restrict__ U1,
                          const float* __restrict__ g0, u16* __restrict__ dst) {
  int i = blockIdx.x * 256 + threadIdx.x;      // < 4096*2048
  int j = i & 7, lane = (i >> 3) & 63, rest = i >> 9;
  int ktg = rest & 63, tmp = rest >> 6;
  int nt = tmp & 3, ug = tmp >> 2;
  int k = ktg * 32 + ((lane >> 4) << 3) + j;
  int rr = nt * 16 + (lane & 15);
  int gate = rr & 3, ul = rr >> 2;
  int col = gate * 1024 + ug * 16 + ul;
  float v = (k < UNITS) ? g0[k] * W1[k * 4096 + col] : U1[(k - UNITS) * 4096 + col];
  dst[i] = f2bf(v);
}

// S1[n] = sum_k g0[k]*W1[k][n];  B1C[n] = b1[n] + sum_k be0[k]*W1[k][n]
__global__ void k_pack_s1(const float* __restrict__ W1, const float* __restrict__ g0,
                          const float* __restrict__ be0, const float* __restrict__ b1,
                          float* __restrict__ S1, float* __restrict__ B1C) {
  int n = blockIdx.x * 256 + threadIdx.x;      // < 4096
  float s = 0.f, c = 0.f;
  for (int k = 0; k < 1024; ++k) {
    float w = W1[k * 4096 + n];
    s += g0[k] * w;
    c += be0[k] * w;
  }
  S1[n] = s;
  B1C[n] = b1[n] + c;
}

// wgfc: B-frags (16x16x32) of g1*Wfc: [s(32)][lane][8], c=lane&15, k=s*32+(lane>>4)*8+j
__global__ void k_pack_wgfc(const float* __restrict__ Wfc, const float* __restrict__ g1,
                            u16* __restrict__ dst) {
  int i = blockIdx.x * 256 + threadIdx.x;      // < 16384
  int j = i & 7, lane = (i >> 3) & 63, s = i >> 9;
  int c = lane & 15;
  int k = s * 32 + ((lane >> 4) << 3) + j;
  dst[i] = f2bf(g1[k] * Wfc[k * 16 + c]);
}

__global__ void k_pack_sfc(const float* __restrict__ Wfc, const float* __restrict__ g1,
                           const float* __restrict__ be1, const float* __restrict__ bfc,
                           float* __restrict__ Sfc, float* __restrict__ Bf) {
  int c = threadIdx.x;
  if (c < 16) {
    float s = 0.f, b = 0.f;
    for (int k = 0; k < 1024; ++k) {
      float w = Wfc[k * 16 + c];
      s += g1[k] * w;
      b += be1[k] * w;
    }
    Sfc[c] = s;
    Bf[c] = bfc[c] + b;
  }
}

// ---------------- persistent kernel ----------------
struct KP {
  const u16* xbf; const u16* wp0; const u16* wp1; const u16* wgfc;
  u16* h0; u16* h1; u32* bar;
  const float* b0; const float* s1; const float* b1c;
  const float* sfc; const float* bfcf;
  float* out;
};

__device__ __forceinline__ void accst4(u32x4 v, float& s1, float& s2) {
#pragma unroll
  for (int e = 0; e < 4; ++e) {
    float f0 = bf2f((u16)(v[e] & 0xffffu));
    float f1 = bf2f((u16)(v[e] >> 16));
    s1 += f0 + f1;
    s2 += f0 * f0 + f1 * f1;
  }
}

// FC + softmax for all 16 rows of this bg via one MFMA on raw h1 (LN folded
// into wgB/sfc/bfcf). Runs on wave0 of the SINGLE block ug==63 (never the
// barrier leader) inside its wait window — off the critical path.
__device__ __forceinline__ void fc_wave0(int lane, int bg, int tout,
    const u16 (*bufB)[1032], const u16* wgB, const float* mu_s, const float* sg_s,
    float sfc_l, float bfc_l, float* __restrict__ out) {
  const int am = lane & 15, aq = (lane >> 4) << 3;
  f32x4 acc = {0.f, 0.f, 0.f, 0.f};
#pragma unroll
  for (int s = 0; s < 32; ++s) {
    bf16x8 a = *(const bf16x8*)&bufB[am][s * 32 + aq];
    bf16x8 b = *(const bf16x8*)&wgB[s * 512 + lane * 8];
    acc = __builtin_amdgcn_mfma_f32_16x16x32_bf16(a, b, acc, 0, 0, 0);
  }
  const int q = lane >> 4;
#pragma unroll
  for (int i = 0; i < 4; ++i) {
    int r = q * 4 + i;
    float rs = sg_s[r], mu = mu_s[r];
    float lg = rs * acc[i] - rs * mu * sfc_l + bfc_l;   // logits[r][c=am]
    float mx = lg;
#pragma unroll
    for (int m = 1; m <= 8; m <<= 1) mx = fmaxf(mx, __shfl_xor(mx, m));
    float e = __expf(lg - mx), ss = e;
#pragma unroll
    for (int m = 1; m <= 8; m <<= 1) ss += __shfl_xor(ss, m);
    out[((size_t)(bg * 16 + r) * T_LEN + tout) * 16 + am] = e / ss;
  }
}

__global__ void __launch_bounds__(512, 2) k_persist(KP p) {
  const int tid = threadIdx.x;
  const int ug = blockIdx.x & 63, bg = blockIdx.x >> 6;
  const int lane = tid & 63, wv = tid >> 6;
  const int nt = wv & 3, kh = wv >> 2;

  __shared__ __align__(16) u16 bufA[16][1032];  // raw h0(t-1), carried across steps
  __shared__ __align__(16) u16 bufB[16][1032];  // raw h1(t-1)
  __shared__ __align__(16) u16 wgB[16384];      // g1*Wfc B-frags, resident
  __shared__ float zb[2][16][68];               // kh-partial z tiles
  __shared__ float b0s[64], b1s[64], S1b[64];
  __shared__ float al_s[16], be_s[16];          // LN0(h0(t)) fold: alpha=rs, beta=-rs*mu
  __shared__ float mu_s[16], sg_s[16];          // LN1 stats of h1(t-1) (for FC)

  if (tid < 64) {
    int gate = tid & 3, ul = tid >> 2;
    int col = gate * 1024 + ug * 16 + ul;
    b0s[tid] = p.b0[col];
    b1s[tid] = p.b1c[col];
    S1b[tid] = p.s1[col];
  }
  for (int i = tid * 8; i < 16384; i += 4096)
    *(uint4*)&wgB[i] = *(const uint4*)(p.wgfc + i);
  {
    u32* za = (u32*)&bufA[0][0];
    u32* zc = (u32*)&bufB[0][0];
    for (int i = tid; i < 16 * 1032 / 2; i += 512) { za[i] = 0u; zc[i] = 0u; }
  }
  const float sfc_l = p.sfc[lane & 15], bfc_l = p.bfcf[lane & 15];

  // resident weight fragments (bf16, MFMA B-operand order); live in the unified
  // VGPR/AGPR file under launch_bounds(512,2) (R1 lesson: default cap => spill)
  bf16x8 w0r[18], w1r[32];
  {
    const u16* q0 = p.wp0 + (size_t)(((ug * 4 + nt) * 36 + kh * 18) * 64 + lane) * 8;
#pragma unroll
    for (int s = 0; s < 18; ++s)
      w0r[s] = __builtin_bit_cast(bf16x8, *(const uint4*)(q0 + (size_t)s * 512));
    const u16* q1 = p.wp1 + (size_t)(((ug * 4 + nt) * 64 + kh * 32) * 64 + lane) * 8;
#pragma unroll
    for (int s = 0; s < 32; ++s)
      w1r[s] = __builtin_bit_cast(bf16x8, *(const uint4*)(q1 + (size_t)s * 512));
  }

  // barrier lines: flags 128B apart (one line per writer, zero line sharing —
  // the R5 killer was 64 writers on ONE line); gen word: single writer, own line.
  u32* flags = p.bar + bg * 2048;               // u32 index; flag ug at +ug*32
  u32* gen   = p.bar + 8192 + bg * 32;

  float c0 = 0.f, c1 = 0.f;                     // cell state, tid<256: (row=tid>>4, unit=tid&15)
  const int gr = tid >> 4, gu = tid & 15;
  const int srow = tid >> 5, ssub = tid & 31;   // row-staging map (32 thr/row)
  const int am = lane & 15, aq = (lane >> 4) << 3;  // A-frag: row=lane&15, k += (lane>>4)*8

  __syncthreads();

  for (int t = 0; t < T_LEN; ++t) {
    const int cur = t & 1, rd = cur ^ 1;

    // ======== L0 MFMA: z0 = [x(t) | h0(t-1)] @ Wp0 ========
    f32x4 acc0 = {0.f, 0.f, 0.f, 0.f};
    if (kh == 0) {
      const u16* xr = p.xbf + (size_t)(t * 64 + bg * 16 + am) * FIN + aq;
#pragma unroll
      for (int s = 0; s < 4; ++s) {            // k in [0,128): x
        bf16x8 a = __builtin_bit_cast(bf16x8, *(const uint4*)(xr + s * 32));
        acc0 = __builtin_amdgcn_mfma_f32_16x16x32_bf16(a, w0r[s], acc0, 0, 0, 0);
      }
#pragma unroll
      for (int s = 4; s < 18; ++s) {           // k in [128,576): h0[0..448)
        bf16x8 a = __builtin_bit_cast(bf16x8, *(const uint4*)&bufA[am][s * 32 + aq - 128]);
        acc0 = __builtin_amdgcn_mfma_f32_16x16x32_bf16(a, w0r[s], acc0, 0, 0, 0);
      }
    } else {
#pragma unroll
      for (int s = 0; s < 18; ++s) {           // k in [576,1152): h0[448..1024)
        bf16x8 a = __builtin_bit_cast(bf16x8, *(const uint4*)&bufA[am][448 + s * 32 + aq]);
        acc0 = __builtin_amdgcn_mfma_f32_16x16x32_bf16(a, w0r[s], acc0, 0, 0, 0);
      }
    }
#pragma unroll
    for (int i = 0; i < 4; ++i)
      zb[kh][(lane >> 4) * 4 + i][nt * 16 + (lane & 15)] = acc0[i];
    __syncthreads();

    // ======== gates layer0 -> coherent store of h0(t) (parity cur) ========
    if (tid < 256) {
      const float* zr0 = &zb[0][gr][gu * 4];
      const float* zr1 = &zb[1][gr][gu * 4];
      float zi = zr0[0] + zr1[0] + b0s[gu * 4 + 0];
      float zf = zr0[1] + zr1[1] + b0s[gu * 4 + 1];
      float zg = zr0[2] + zr1[2] + b0s[gu * 4 + 2];
      float zo = zr0[3] + zr1[3] + b0s[gu * 4 + 3];
      float gi = sigm(zi), gf = sigm(zf), gg = tanhft(zg), go = sigm(zo);
      c0 = gf * c0 + gi * gg;
      float h = go * tanhft(c0);
      sth(p.h0 + (size_t)cur * H_STRIDE + (size_t)(bg * 16 + gr) * UNITS + ug * 16 + gu,
          f2bf(h));
    }
    __syncthreads();                            // drains h0 stores (vmcnt(0) before s_barrier)

    // ---- barrier (leader/gen, RELAXED only); FC(t-2) hides in ug==63's window ----
    {
      const u32 ep = (u32)(t + 1);
      if (wv == 0) {
        if (lane == 0)
          __hip_atomic_store(flags + ug * 32, ep, __ATOMIC_RELAXED, __HIP_MEMORY_SCOPE_AGENT);
        if (ug == 63 && t >= 2)
          fc_wave0(lane, bg, t - 2, bufB, wgB, mu_s, sg_s, sfc_l, bfc_l, p.out);
        if (ug == 0) {
          for (;;) {
            u32 v = __hip_atomic_load(flags + lane * 32, __ATOMIC_RELAXED, __HIP_MEMORY_SCOPE_AGENT);
            if (__ballot(v >= ep) == ~0ull) break;
            __builtin_amdgcn_s_sleep(1);
          }
          if (lane == 0)
            __hip_atomic_store(gen, ep, __ATOMIC_RELAXED, __HIP_MEMORY_SCOPE_AGENT);
        } else {
          // all lanes load the same address -> coalesces to ONE LLC request
          while (__hip_atomic_load(gen, __ATOMIC_RELAXED, __HIP_MEMORY_SCOPE_AGENT) < ep)
            __builtin_amdgcn_s_sleep(1);
        }
      }
      __syncthreads();
    }

    // ======== overlapped gather: h0(t)[cur] + h1(t-1)[rd], one LLC round-trip ========
    {
      const u16* h0r = p.h0 + (size_t)cur * H_STRIDE + (size_t)(bg * 16 + srow) * UNITS + ssub * 8;
      const u16* h1r = p.h1 + (size_t)rd  * H_STRIDE + (size_t)(bg * 16 + srow) * UNITS + ssub * 8;
      u32x4 a0, a1, a2, a3, b0, b1, b2, b3;
      ldh2x64(h0r, h1r, a0, a1, a2, a3, b0, b1, b2, b3);

      float s1 = 0.f, s2 = 0.f;
      accst4(a0, s1, s2); accst4(a1, s1, s2); accst4(a2, s1, s2); accst4(a3, s1, s2);
#pragma unroll
      for (int m = 1; m <= 16; m <<= 1) { s1 += __shfl_xor(s1, m); s2 += __shfl_xor(s2, m); }
      if (ssub == 0) {
        float mu = s1 * (1.0f / 1024.0f);
        float rs = rsqrtf(s2 * (1.0f / 1024.0f) - mu * mu + 1e-3f);
        al_s[srow] = rs;
        be_s[srow] = -rs * mu;
      }
      float u1 = 0.f, u2 = 0.f;
      accst4(b0, u1, u2); accst4(b1, u1, u2); accst4(b2, u1, u2); accst4(b3, u1, u2);
#pragma unroll
      for (int m = 1; m <= 16; m <<= 1) { u1 += __shfl_xor(u1, m); u2 += __shfl_xor(u2, m); }
      if (ssub == 0) {
        float mu = u1 * (1.0f / 1024.0f);
        mu_s[srow] = mu;
        sg_s[srow] = rsqrtf(u2 * (1.0f / 1024.0f) - mu * mu + 1e-3f);
      }
      *(u32x4*)&bufA[srow][ssub * 8]       = a0;
      *(u32x4*)&bufA[srow][256 + ssub * 8] = a1;
      *(u32x4*)&bufA[srow][512 + ssub * 8] = a2;
      *(u32x4*)&bufA[srow][768 + ssub * 8] = a3;
      *(u32x4*)&bufB[srow][ssub * 8]       = b0;
      *(u32x4*)&bufB[srow][256 + ssub * 8] = b1;
      *(u32x4*)&bufB[srow][512 + ssub * 8] = b2;
      *(u32x4*)&bufB[srow][768 + ssub * 8] = b3;
    }
    __syncthreads();

    // ======== L1 MFMA on RAW h: kh0 = h0(t)@(g0*W1), kh1 = h1(t-1)@U1 ========
    f32x4 acc1 = {0.f, 0.f, 0.f, 0.f};
    if (kh == 0) {
#pragma unroll
      for (int s = 0; s < 32; ++s) {
        bf16x8 a = __builtin_bit_cast(bf16x8, *(const uint4*)&bufA[am][s * 32 + aq]);
        acc1 = __builtin_amdgcn_mfma_f32_16x16x32_bf16(a, w1r[s], acc1, 0, 0, 0);
      }
    } else {
#pragma unroll
      for (int s = 0; s < 32; ++s) {
        bf16x8 a = __builtin_bit_cast(bf16x8, *(const uint4*)&bufB[am][s * 32 + aq]);
        acc1 = __builtin_amdgcn_mfma_f32_16x16x32_bf16(a, w1r[s], acc1, 0, 0, 0);
      }
    }
#pragma unroll
    for (int i = 0; i < 4; ++i)
      zb[kh][(lane >> 4) * 4 + i][nt * 16 + (lane & 15)] = acc1[i];
    __syncthreads();

    // ======== gates layer1 (LN0 applied as per-row affine) -> h1(t) store ========
    if (tid < 256) {
      const float al = al_s[gr], be = be_s[gr];
      const float* zr0 = &zb[0][gr][gu * 4];
      const float* zr1 = &zb[1][gr][gu * 4];
      float zi = al * zr0[0] + be * S1b[gu * 4 + 0] + zr1[0] + b1s[gu * 4 + 0];
      float zf = al * zr0[1] + be * S1b[gu * 4 + 1] + zr1[1] + b1s[gu * 4 + 1];
      float zg = al * zr0[2] + be * S1b[gu * 4 + 2] + zr1[2] + b1s[gu * 4 + 2];
      float zo = al * zr0[3] + be * S1b[gu * 4 + 3] + zr1[3] + b1s[gu * 4 + 3];
      float gi = sigm(zi), gf = sigm(zf), gg = tanhft(zg), go = sigm(zo);
      c1 = gf * c1 + gi * gg;
      float h = go * tanhft(c1);
      sth(p.h1 + (size_t)cur * H_STRIDE + (size_t)(bg * 16 + gr) * UNITS + ug * 16 + gu,
          f2bf(h));
    }
    __syncthreads();  // R4 race fix: protect zb from next step's L0 writes
  }

  // ======== epilogue: FC(510) from current bufB; then gather h1(511) -> FC(511) ====
  {
    const u32 ep = (u32)(T_LEN + 1);
    if (wv == 0) {
      if (lane == 0)
        __hip_atomic_store(flags + ug * 32, ep, __ATOMIC_RELAXED, __HIP_MEMORY_SCOPE_AGENT);
      if (ug == 63)
        fc_wave0(lane, bg, T_LEN - 2, bufB, wgB, mu_s, sg_s, sfc_l, bfc_l, p.out);
      if (ug == 0) {
        for (;;) {
          u32 v = __hip_atomic_load(flags + lane * 32, __ATOMIC_RELAXED, __HIP_MEMORY_SCOPE_AGENT);
          if (__ballot(v >= ep) == ~0ull) break;
          __builtin_amdgcn_s_sleep(1);
        }
        if (lane == 0)
          __hip_atomic_store(gen, ep, __ATOMIC_RELAXED, __HIP_MEMORY_SCOPE_AGENT);
      } else {
        while (__hip_atomic_load(gen, __ATOMIC_RELAXED, __HIP_MEMORY_SCOPE_AGENT) < ep)
          __builtin_amdgcn_s_sleep(1);
      }
    }
    __syncthreads();
  }
  {
    const u16* h1r = p.h1 + (size_t)((T_LEN - 1) & 1) * H_STRIDE
                   + (size_t)(bg * 16 + srow) * UNITS + ssub * 8;
    u32x4 b0, b1, b2, b3;
    ldh1x64(h1r, b0, b1, b2, b3);
    float u1 = 0.f, u2 = 0.f;
    accst4(b0, u1, u2); accst4(b1, u1, u2); accst4(b2, u1, u2); accst4(b3, u1, u2);
#pragma unroll
    for (int m = 1; m <= 16; m <<= 1) { u1 += __shfl_xor(u1, m); u2 += __shfl_xor(u2, m); }
    if (ssub == 0) {
      float mu = u1 * (1.0f / 1024.0f);
      mu_s[srow] = mu;
      sg_s[srow] = rsqrtf(u2 * (1.0f / 1024.0f) - mu * mu + 1e-3f);
    }
    *(u32x4*)&bufB[srow][ssub * 8]       = b0;
    *(u32x4*)&bufB[srow][256 + ssub * 8] = b1;
    *(u32x4*)&bufB[srow][512 + ssub * 8] = b2;
    *(u32x4*)&bufB[srow][768 + ssub * 8] = b3;
  }
  __syncthreads();
  if (ug == 63 && wv == 0)
    fc_wave0(lane, bg, T_LEN - 1, bufB, wgB, mu_s, sg_s, sfc_l, bfc_l, p.out);
}

extern "C" void kernel_launch(void* const* d_in, const int* in_sizes, int n_in,
                              void* d_out, int out_size, void* d_ws, size_t ws_size,
                              hipStream_t stream) {
  (void)in_sizes; (void)n_in; (void)out_size;
  if (ws_size < (size_t)WS_NEED) return;

  const float* inp = (const float*)d_in[0];
  const float* W0  = (const float*)d_in[1];
  const float* U0  = (const float*)d_in[2];
  const float* b0  = (const float*)d_in[3];
  const float* g0  = (const float*)d_in[4];
  const float* be0 = (const float*)d_in[5];
  const float* W1  = (const float*)d_in[6];
  const float* U1  = (const float*)d_in[7];
  const float* b1  = (const float*)d_in[8];
  const float* g1  = (const float*)d_in[9];
  const float* be1 = (const float*)d_in[10];
  const float* Wfc = (const float*)d_in[11];
  const float* bfc = (const float*)d_in[12];

  char* ws = (char*)d_ws;
  u32* bar  = (u32*)(ws + O_BAR);
  u16* xbf  = (u16*)(ws + O_XBF);
  u16* wp0  = (u16*)(ws + O_WP0);
  u16* wp1  = (u16*)(ws + O_WP1);
  u16* wgfc = (u16*)(ws + O_WGFC);
  float* S1   = (float*)(ws + O_S1);
  float* B1C  = (float*)(ws + O_B1C);
  float* Sfc  = (float*)(ws + O_SFC);
  float* Bf   = (float*)(ws + O_BFCF);
  u16* h0   = (u16*)(ws + O_H0);
  u16* h1   = (u16*)(ws + O_H1);

  k_zero<<<64, 256, 0, stream>>>(bar, 16384);
  k_zero<<<512, 256, 0, stream>>>((u32*)(ws + O_H0), (SZ_H + SZ_H) / 4);
  k_pack_x<<<16384, 256, 0, stream>>>(inp, xbf);
  k_pack_w0<<<18432, 256, 0, stream>>>(W0, U0, wp0);
  k_pack_w1<<<32768, 256, 0, stream>>>(W1, U1, g0, wp1);
  k_pack_s1<<<16, 256, 0, stream>>>(W1, g0, be0, b1, S1, B1C);
  k_pack_wgfc<<<64, 256, 0, stream>>>(Wfc, g1, wgfc);
  k_pack_sfc<<<1, 64, 0, stream>>>(Wfc, g1, be1, bfc, Sfc, Bf);

  KP p;
  p.xbf = xbf; p.wp0 = wp0; p.wp1 = wp1; p.wgfc = wgfc;
  p.h0 = h0; p.h1 = h1; p.bar = bar;
  p.b0 = b0; p.s1 = S1; p.b1c = B1C;
  p.sfc = Sfc; p.bfcf = Bf;
  p.out = (float*)d_out;

  void* args[] = { &p };
  hipLaunchCooperativeKernel((const void*)k_persist, dim3(256), dim3(512), args, 0, stream);
}